// Round 9
// baseline (12802.547 us; speedup 1.0000x reference)
//
#include <hip/hip_runtime.h>

// RNN echo-state scan on MI355X — round 9.
// Protocol = r6-PROVEN, verbatim: sc1 write-through publish -> per-wave
// vmcnt(0) drain -> agent-atomic counter post; consumer agent-atomic poll ->
// acquire-fence (buffer_inv) -> batched plain loads (inline asm, single drain).
// NO startup barrier, NO XCC introspection, NO sc0 fast path (r7/r8 deadlocks).
// New vs r6 (performance-only changes): 8 groups x 16 WGs (group = wg&7 so
// members share an XCD under round-robin dispatch -- heuristic only), 8
// batches/group, 64 cols/WG, f16 single-plane W (LDS 139,264B exact) and f16
// exchange (error 2^-12/step, ~6x smaller than r6's measured-0.031 bf16 path).

#define TT    2048
#define BB    64
#define NIN   64
#define NRECN 1024
#define KTOT  1088
#define NGRP  8
#define WPGRP 16
#define NWG   128
#define NOISE_STD 0.001f

typedef __attribute__((ext_vector_type(8))) _Float16 half8;
typedef __attribute__((ext_vector_type(4))) float f32x4;

// Write-through, agent-coherent 2B store (proven r2/r4/r6).
__device__ __forceinline__ void st_h_sc1(_Float16* p, unsigned short u) {
  unsigned v = u;
  asm volatile("global_store_short %0, %1, off sc1" :: "v"(p), "v"(v) : "memory");
}
__device__ __forceinline__ void split8h(const f32x4& v0, const f32x4& v1,
                                        half8& hh, half8& hl) {
  #pragma unroll
  for (int j = 0; j < 4; ++j) {
    _Float16 h = (_Float16)v0[j];
    hh[j] = h; hl[j] = (_Float16)(v0[j] - (float)h);
  }
  #pragma unroll
  for (int j = 0; j < 4; ++j) {
    _Float16 h = (_Float16)v1[j];
    hh[4 + j] = h; hl[4 + j] = (_Float16)(v1[j] - (float)h);
  }
}

// Batched 16B plain load (L2-cached), immediate offset (max 1984 here, <4095).
#define LDA16(V, P, OFF) \
  asm volatile("global_load_dwordx4 %0, %1, off offset:%c2" \
               : "=&v"(V) : "v"(P), "n"(OFF))

#define MFMA16 __builtin_amdgcn_mfma_f32_16x16x32_f16

__global__ __launch_bounds__(128, 1) void rnn_scan_kernel(
    const float* __restrict__ x, const float* __restrict__ W_ih,
    const float* __restrict__ W_hh, const float* __restrict__ noise,
    float* __restrict__ out, int* __restrict__ flags,
    _Float16* __restrict__ th)
{
  extern __shared__ _Float16 smem[];   // W f16, sub-chunk-major [136][64][8]

  const int wg = blockIdx.x, grp = wg & 7, gidx = wg >> 3;
  const int tid = threadIdx.x, lane = tid & 63, wv = tid >> 6;
  const int l15 = lane & 15, g4 = lane >> 4;

  // one-time: W slice (cols gidx*64..+64, K=1088) -> LDS f16
  for (int idx = tid; idx < 64 * KTOT; idx += 128) {
    int nr = idx / KTOT, k = idx - nr * KTOT;
    int ng = gidx * 64 + nr;
    float v = (k < NRECN) ? W_hh[(size_t)ng * NRECN + k]
                          : W_ih[(size_t)ng * NIN + (k - NRECN)];
    smem[(k >> 3) * 512 + nr * 8 + (k & 7)] = (_Float16)v;
  }
  __syncthreads();

  int* flags_g = flags + grp * WPGRP * 16;      // 16 counters x 64B per group
  const _Float16* whp0 = smem + g4 * 512 + (wv * 32 + l15) * 8; // +c*2048/chunk
  const _Float16* whp1 = whp0 + 128;            // second 16-col fragment
  _Float16* thg = th + grp * (2 * 16 * 1024);   // [buf][16 rows][1024] f16
  const int b_eff = grp * 8 + (l15 & 7);        // pad A rows 8..15 clamp
  const float* xrow = x + (size_t)b_eff * TT * NIN;
  const int col0 = gidx * 64 + wv * 32 + l15, col1 = col0 + 16;

  for (int t = 0; t < TT; ++t) {
    const int buf = t & 1;

    // ---- x part (K chunks 32,33), f16 hi/lo split — overlaps the poll below
    const float* xp = xrow + (size_t)t * NIN + g4 * 8;
    f32x4 v0 = *(const f32x4*)xp,        v1 = *(const f32x4*)(xp + 4);
    f32x4 v2 = *(const f32x4*)(xp + 32), v3 = *(const f32x4*)(xp + 36);
    const float nz0 = noise[(size_t)t * NRECN + col0] * NOISE_STD;
    const float nz1 = noise[(size_t)t * NRECN + col1] * NOISE_STD;

    f32x4 P0{0,0,0,0}, P1{0,0,0,0}, Q0{0,0,0,0}, Q1{0,0,0,0};
    {
      half8 xh, xl;
      split8h(v0, v1, xh, xl);
      half8 b0 = *(const half8*)(whp0 + 32 * 2048);
      half8 b1 = *(const half8*)(whp1 + 32 * 2048);
      P0 = MFMA16(xh, b0, P0, 0,0,0); P1 = MFMA16(xh, b1, P1, 0,0,0);
      Q0 = MFMA16(xl, b0, Q0, 0,0,0); Q1 = MFMA16(xl, b1, Q1, 0,0,0);
      split8h(v2, v3, xh, xl);
      b0 = *(const half8*)(whp0 + 33 * 2048);
      b1 = *(const half8*)(whp1 + 33 * 2048);
      P0 = MFMA16(xh, b0, P0, 0,0,0); P1 = MFMA16(xh, b1, P1, 0,0,0);
      Q0 = MFMA16(xl, b0, Q0, 0,0,0); Q1 = MFMA16(xl, b1, Q1, 0,0,0);
    }

    // ---- recurrent part (r6-proven consume protocol)
    if (t > 0) {
      const int t2 = t << 1;                     // 2 posts/WG/step
      if (lane < WPGRP) {
        while (__hip_atomic_load(&flags_g[lane * 16], __ATOMIC_RELAXED,
                                 __HIP_MEMORY_SCOPE_AGENT) < t2) { }
      }
      __builtin_amdgcn_fence(__ATOMIC_ACQUIRE, "agent");  // buffer_inv

      // batched A loads: 32 x 16B = 128 VGPR, single drain, imm offs 0..1984
      const _Float16* abase = thg + buf * 16384 + l15 * 1024 + g4 * 8;
      half8 A[32];
      #pragma unroll
      for (int c = 0; c < 32; ++c) LDA16(A[c], abase, c * 64);
      asm volatile("s_waitcnt vmcnt(0)" ::: "memory");
      __builtin_amdgcn_sched_barrier(0);

      #pragma unroll
      for (int c = 0; c < 32; c += 2) {
        half8 e0 = *(const half8*)(whp0 + c * 2048);
        half8 e1 = *(const half8*)(whp1 + c * 2048);
        half8 o0 = *(const half8*)(whp0 + (c + 1) * 2048);
        half8 o1 = *(const half8*)(whp1 + (c + 1) * 2048);
        P0 = MFMA16(A[c],   e0, P0, 0,0,0); P1 = MFMA16(A[c],   e1, P1, 0,0,0);
        Q0 = MFMA16(A[c+1], o0, Q0, 0,0,0); Q1 = MFMA16(A[c+1], o1, Q1, 0,0,0);
      }
    }

    // ---- epilogue: h, tanh, f16 sc1 publish (rows 0..7 valid; 8..15 pad)
    f32x4 h0 = P0 + Q0, h1 = P1 + Q1;
    _Float16* ob = thg + ((t + 1) & 1) * 16384;
    float ho0[4], ho1[4];
    #pragma unroll
    for (int r = 0; r < 4; ++r) {
      const int mr = g4 * 4 + r;                 // C-frag row (m89 layout)
      float a0 = h0[r] + nz0, a1 = h1[r] + nz1;
      ho0[r] = a0; ho1[r] = a1;
      if (mr < 8) {
        float t0 = 1.f - 2.f / (__expf(2.f * a0) + 1.f);
        float t1 = 1.f - 2.f / (__expf(2.f * a1) + 1.f);
        st_h_sc1(ob + mr * 1024 + col0,
                 __builtin_bit_cast(unsigned short, (_Float16)t0));
        st_h_sc1(ob + mr * 1024 + col1,
                 __builtin_bit_cast(unsigned short, (_Float16)t1));
      }
    }
    asm volatile("s_waitcnt vmcnt(0)" ::: "memory");  // my th stores at MALL
    if (lane == 0)
      __hip_atomic_fetch_add(&flags_g[gidx * 16], 1, __ATOMIC_RELAXED,
                             __HIP_MEMORY_SCOPE_AGENT);

    // ---- outputs, off the critical path (after flag post)
    if (grp == NGRP - 1 || t == TT - 1) {
      #pragma unroll
      for (int r = 0; r < 4; ++r) {
        const int mr = g4 * 4 + r;
        if (mr < 8) {
          const int br = grp * 8 + mr;
          if (br == BB - 1) {
            out[(size_t)col0 * TT + t] = ho0[r];
            out[(size_t)col1 * TT + t] = ho1[r];
          }
          if (t == TT - 1) {
            out[(size_t)NRECN * TT + (size_t)br * NRECN + col0] = ho0[r];
            out[(size_t)NRECN * TT + (size_t)br * NRECN + col1] = ho1[r];
          }
        }
      }
    }
  }
}

extern "C" void kernel_launch(void* const* d_in, const int* in_sizes, int n_in,
                              void* d_out, int out_size, void* d_ws, size_t ws_size,
                              hipStream_t stream) {
  const float* x     = (const float*)d_in[0];
  const float* W_ih  = (const float*)d_in[1];
  const float* W_hh  = (const float*)d_in[2];
  const float* noise = (const float*)d_in[3];
  float* out = (float*)d_out;

  char* ws = (char*)d_ws;
  int* flags = (int*)ws;                         // 8 grp x 16 ctr x 64B = 8KB
  _Float16* th = (_Float16*)(ws + 8192);         // [8][2][16][1024] f16, 512KB
  // ws usage: 8192 + 524288 = 532,480 bytes.
  // th pad rows 8..15 are never written and feed only discarded C rows.

  (void)hipMemsetAsync(flags, 0, 8192, stream);  // deterministic replays

  const size_t lds_bytes = (size_t)136 * 64 * 8 * sizeof(_Float16); // 139,264
  (void)hipFuncSetAttribute((const void*)rnn_scan_kernel,
                            hipFuncAttributeMaxDynamicSharedMemorySize,
                            (int)lds_bytes);

  rnn_scan_kernel<<<dim3(NWG), dim3(128), lds_bytes, stream>>>(
      x, W_ih, W_hh, noise, out, flags, th);
}